// Round 1
// baseline (885.723 us; speedup 1.0000x reference)
//
#include <hip/hip_runtime.h>

#define BLK 256

// ---------------------------------------------------------------------------
// Geometry:
//   3 scales s=0,1,2 with base resolution R_s = 512<<s, 8 channels, 3 planes.
//   Mip levels l=0..7, size R>>l.  off(l) = sum_{j<l}(R>>j)^2 = 4*(R^2-(R>>l)^2)/3.
//   Sampling level range: scale0 uses l in [0,7], scale1 [1,7], scale2 [2,7].
//   Workspace holds per scale the levels [Lmin..7], level-major, each level
//   block = [3 planes][sz][sz][8ch] floats.
//   WOFF (float offsets into ws): scale0=0, scale1=2097024, scale2=10485120.
//   OFFMIN (texel off(Lmin) per scale): {262144, 1048576, 5242880}.
// ---------------------------------------------------------------------------

__device__ __forceinline__ float4 f4_fma(const float4 a, const float w, const float4 acc) {
    float4 r;
    r.x = fmaf(a.x, w, acc.x);
    r.y = fmaf(a.y, w, acc.y);
    r.z = fmaf(a.z, w, acc.z);
    r.w = fmaf(a.w, w, acc.w);
    return r;
}

__device__ __forceinline__ void bilerp(const float4* __restrict__ t, int sz, float u, float v,
                                       float4& o0, float4& o1) {
    float fsz = (float)sz;
    float px = u * fsz - 0.5f;
    float py = v * fsz - 0.5f;
    float x0f = floorf(px), y0f = floorf(py);
    float fx = px - x0f, fy = py - y0f;
    int xi = (int)x0f, yi = (int)y0f;
    int m = sz - 1;
    int x0 = min(max(xi, 0), m);
    int x1 = min(max(xi + 1, 0), m);
    int y0 = min(max(yi, 0), m);
    int y1 = min(max(yi + 1, 0), m);
    const float4* r0 = t + (size_t)y0 * sz * 2;
    const float4* r1 = t + (size_t)y1 * sz * 2;
    float4 v00a = r0[x0 * 2], v00b = r0[x0 * 2 + 1];
    float4 v01a = r0[x1 * 2], v01b = r0[x1 * 2 + 1];
    float4 v10a = r1[x0 * 2], v10b = r1[x0 * 2 + 1];
    float4 v11a = r1[x1 * 2], v11b = r1[x1 * 2 + 1];
    float w00 = (1.0f - fx) * (1.0f - fy);
    float w01 = fx * (1.0f - fy);
    float w10 = (1.0f - fx) * fy;
    float w11 = fx * fy;
    float4 z = make_float4(0.f, 0.f, 0.f, 0.f);
    float4 a0 = f4_fma(v00a, w00, z);
    a0 = f4_fma(v01a, w01, a0);
    a0 = f4_fma(v10a, w10, a0);
    a0 = f4_fma(v11a, w11, a0);
    float4 a1 = f4_fma(v00b, w00, z);
    a1 = f4_fma(v01b, w01, a1);
    a1 = f4_fma(v10b, w10, a1);
    a1 = f4_fma(v11b, w11, a1);
    o0 = a0;
    o1 = a1;
}

// 2x2 box-filter downsample; handles up to 3 independent (src,dst) pairs.
__global__ void __launch_bounds__(BLK) down2_kernel(
    const float* __restrict__ sA, const float* __restrict__ sB, const float* __restrict__ sC,
    float* __restrict__ dA, float* __restrict__ dB, float* __restrict__ dC,
    int lszA, int lszB, int lszC, int bA, int bB, int bC) {
    int j = blockIdx.x * blockDim.x + threadIdx.x;
    if (j >= bC) return;
    const float* src;
    float* dst;
    int lsz;
    if (j < bA) {
        src = sA; dst = dA; lsz = lszA;
    } else if (j < bB) {
        src = sB; dst = dB; lsz = lszB; j -= bA;
    } else {
        src = sC; dst = dC; lsz = lszC; j -= bB;
    }
    int sz = 1 << lsz;
    int p = j >> (2 * lsz + 1);
    int rem = j & ((1 << (2 * lsz + 1)) - 1);
    int half = rem & 1;
    int tex = rem >> 1;
    int y = tex >> lsz;
    int x = tex & (sz - 1);
    int S = sz << 1;
    const float4* sp = (const float4*)src + (size_t)p * S * S * 2;
    size_t i00 = ((size_t)(2 * y) * S + 2 * x) * 2 + half;
    float4 a = sp[i00];
    float4 b = sp[i00 + 2];
    float4 c = sp[i00 + (size_t)2 * S];
    float4 d = sp[i00 + (size_t)2 * S + 2];
    float4 r;
    r.x = (a.x + b.x + c.x + d.x) * 0.25f;
    r.y = (a.y + b.y + c.y + d.y) * 0.25f;
    r.z = (a.z + b.z + c.z + d.z) * 0.25f;
    r.w = (a.w + b.w + c.w + d.w) * 0.25f;
    ((float4*)dst)[j] = r;
}

// 4x4 box-filter downsample (one src/dst) -- used to build grid2 level2
// directly from level0, skipping the never-sampled level1.
__global__ void __launch_bounds__(BLK) down4_kernel(
    const float* __restrict__ src, float* __restrict__ dst, int lsz, int total) {
    int j = blockIdx.x * blockDim.x + threadIdx.x;
    if (j >= total) return;
    int sz = 1 << lsz;
    int p = j >> (2 * lsz + 1);
    int rem = j & ((1 << (2 * lsz + 1)) - 1);
    int half = rem & 1;
    int tex = rem >> 1;
    int y = tex >> lsz;
    int x = tex & (sz - 1);
    int S = sz << 2;
    const float4* sp = (const float4*)src + (size_t)p * S * S * 2;
    float4 acc = make_float4(0.f, 0.f, 0.f, 0.f);
#pragma unroll
    for (int dy = 0; dy < 4; ++dy) {
#pragma unroll
        for (int dx = 0; dx < 4; ++dx) {
            size_t idx = ((size_t)(4 * y + dy) * S + (4 * x + dx)) * 2 + half;
            float4 v = sp[idx];
            acc.x += v.x;
            acc.y += v.y;
            acc.z += v.z;
            acc.w += v.w;
        }
    }
    float4 r;
    r.x = acc.x * 0.0625f;
    r.y = acc.y * 0.0625f;
    r.z = acc.z * 0.0625f;
    r.w = acc.w * 0.0625f;
    ((float4*)dst)[j] = r;
}

__global__ void __launch_bounds__(BLK) tex_sample_kernel(
    const float* __restrict__ xin, const float* __restrict__ level,
    const float* __restrict__ g0, const float* __restrict__ ws,
    float* __restrict__ out, int n) {
    int i = blockIdx.x * blockDim.x + threadIdx.x;
    if (i >= n) return;
    float xv0 = xin[3 * i + 0];
    float xv1 = xin[3 * i + 1];
    float xv2 = xin[3 * i + 2];
    float lev = level[i];
    float* op = out + (size_t)i * 72;

    const int WOFF_[3] = {0, 2097024, 10485120};
    const int OFFMIN_[3] = {262144, 1048576, 5242880};

#pragma unroll
    for (int s = 0; s < 3; ++s) {
        const int R = 512 << s;
        float bias = (lev + 9.0f) + (float)s;
        float lvl = fminf(fmaxf(bias, 0.0f), 7.0f);
        float l0f = floorf(lvl);
        int l0 = (int)l0f;
        int l1 = min(l0 + 1, 7);
        float f = lvl - l0f;
        int sz0 = R >> l0;
        int sz1 = R >> l1;
        int off0 = ((R * R - sz0 * sz0) * 4) / 3;  // off(l0) in texels (per plane)
        int off1 = ((R * R - sz1 * sz1) * 4) / 3;
        const float* wbase = ws + WOFF_[s];
        // ws level block start = 24*(off(l)-off(Lmin)) floats = 6*(...) float4s
        const float4* base0 = (l0 == 0) ? (const float4*)g0
                                        : (const float4*)wbase + (size_t)(off0 - OFFMIN_[s]) * 6;
        const float4* base1 = (const float4*)wbase + (size_t)(off1 - OFFMIN_[s]) * 6;  // l1 >= 1 always

#pragma unroll
        for (int p = 0; p < 3; ++p) {
            float u = (p == 0) ? xv1 : xv0;
            float v = (p == 2) ? xv1 : xv2;
            const float4* t0 = base0 + (size_t)p * (sz0 * sz0 * 2);
            const float4* t1 = base1 + (size_t)p * (sz1 * sz1 * 2);
            float4 a0, a1, b0, b1;
            bilerp(t0, sz0, u, v, a0, a1);
            bilerp(t1, sz1, u, v, b0, b1);
            float omf = 1.0f - f;
            float4 r0, r1;
            r0.x = a0.x * omf + b0.x * f;
            r0.y = a0.y * omf + b0.y * f;
            r0.z = a0.z * omf + b0.z * f;
            r0.w = a0.w * omf + b0.w * f;
            r1.x = a1.x * omf + b1.x * f;
            r1.y = a1.y * omf + b1.y * f;
            r1.z = a1.z * omf + b1.z * f;
            r1.w = a1.w * omf + b1.w * f;
            float4* o4 = (float4*)(op + s * 24 + p * 8);
            o4[0] = r0;
            o4[1] = r1;
        }
    }
}

extern "C" void kernel_launch(void* const* d_in, const int* in_sizes, int n_in,
                              void* d_out, int out_size, void* d_ws, size_t ws_size,
                              hipStream_t stream) {
    const float* x = (const float*)d_in[0];
    const float* level = (const float*)d_in[1];
    const float* g[3] = {(const float*)d_in[2], (const float*)d_in[3], (const float*)d_in[4]};
    float* out = (float*)d_out;
    float* ws = (float*)d_ws;
    int n = in_sizes[0] / 3;

    const size_t WOFF[3] = {0, 2097024, 10485120};
    const int OFFMIN[3] = {262144, 1048576, 5242880};
    auto wsBlock = [&](int s, int l) -> float* {
        int R = 512 << s;
        int sz = R >> l;
        int off = ((R * R - sz * sz) * 4) / 3;
        return ws + WOFF[s] + (size_t)(off - OFFMIN[s]) * 24;
    };

    // ---- pyramid build ----
    // l=1 : scales 0,1 from base grids
    {
        int nA = 3 * 256 * 256 * 2;
        int nB = 3 * 512 * 512 * 2;
        int bA = nA, bB = nA + nB, bC = bB;
        down2_kernel<<<(bC + BLK - 1) / BLK, BLK, 0, stream>>>(
            g[0], g[1], g[0],
            wsBlock(0, 1), wsBlock(1, 1), wsBlock(0, 1),
            8, 9, 8, bA, bB, bC);
    }
    // l=2 : scales 0,1 from ws level1
    {
        int nA = 3 * 128 * 128 * 2;
        int nB = 3 * 256 * 256 * 2;
        int bA = nA, bB = nA + nB, bC = bB;
        down2_kernel<<<(bC + BLK - 1) / BLK, BLK, 0, stream>>>(
            wsBlock(0, 1), wsBlock(1, 1), wsBlock(0, 1),
            wsBlock(0, 2), wsBlock(1, 2), wsBlock(0, 2),
            7, 8, 7, bA, bB, bC);
    }
    // l=2 : scale 2 directly from base grid (4x4 box), level1 never sampled
    {
        int total = 3 * 512 * 512 * 2;
        down4_kernel<<<(total + BLK - 1) / BLK, BLK, 0, stream>>>(
            g[2], wsBlock(2, 2), 9, total);
    }
    // l=3..7 : all three scales from ws
    for (int l = 3; l <= 7; ++l) {
        int szA = 512 >> l, szB = 1024 >> l, szC = 2048 >> l;
        int nA = 3 * szA * szA * 2;
        int nB = 3 * szB * szB * 2;
        int nC = 3 * szC * szC * 2;
        int bA = nA, bB = nA + nB, bC = nA + nB + nC;
        down2_kernel<<<(bC + BLK - 1) / BLK, BLK, 0, stream>>>(
            wsBlock(0, l - 1), wsBlock(1, l - 1), wsBlock(2, l - 1),
            wsBlock(0, l), wsBlock(1, l), wsBlock(2, l),
            9 - l, 10 - l, 11 - l, bA, bB, bC);
    }

    // ---- sampling ----
    tex_sample_kernel<<<(n + BLK - 1) / BLK, BLK, 0, stream>>>(
        x, level, g[0], ws, out, n);
}

// Round 2
// 542.921 us; speedup vs baseline: 1.6314x; 1.6314x over previous
//
#include <hip/hip_runtime.h>

#define BLK 256

// ---------------------------------------------------------------------------
// All pyramid levels stored in ws as bf16 texels: 8ch x 2B = 16B = one uint4.
// Scales s=0,1,2, base R = 512<<s, planes-major per level: [3][sz][sz] texels.
// Level ranges: scale0 L0-7, scale1 L1-7 (L0 never sampled), scale2 L2-7.
// ws texel offsets (1 texel = 16B):
//   T0 (scale0 base, L0) = 0
//   T1 (scale1 base, L1) = 1048560
//   T2 (scale2 base, L2) = 2097072
//   total = 3145392 texels = 50.3 MB
// Per-plane texel offset of level l at base R: off(R,l) = (R^2-(R>>l)^2)*4/3.
// OFFMIN per scale = off(R, Lmin) = {0, 1048576, 5242880}.
// ---------------------------------------------------------------------------

#define T0 0
#define T1 1048560
#define T2 2097072

__device__ __forceinline__ unsigned bfrne(float x) {
    unsigned u = __float_as_uint(x);
    return (u + 0x7fffu + ((u >> 16) & 1u)) >> 16;
}

__device__ __forceinline__ uint4 pack8(const float o[8]) {
    uint4 q;
    q.x = bfrne(o[0]) | (bfrne(o[1]) << 16);
    q.y = bfrne(o[2]) | (bfrne(o[3]) << 16);
    q.z = bfrne(o[4]) | (bfrne(o[5]) << 16);
    q.w = bfrne(o[6]) | (bfrne(o[7]) << 16);
    return q;
}

__device__ __forceinline__ void dec8(const uint4 q, float o[8]) {
    o[0] = __uint_as_float(q.x << 16);
    o[1] = __uint_as_float(q.x & 0xffff0000u);
    o[2] = __uint_as_float(q.y << 16);
    o[3] = __uint_as_float(q.y & 0xffff0000u);
    o[4] = __uint_as_float(q.z << 16);
    o[5] = __uint_as_float(q.z & 0xffff0000u);
    o[6] = __uint_as_float(q.w << 16);
    o[7] = __uint_as_float(q.w & 0xffff0000u);
}

__device__ __forceinline__ void acc8(const uint4 q, float w, float o[8]) {
    o[0] = fmaf(__uint_as_float(q.x << 16), w, o[0]);
    o[1] = fmaf(__uint_as_float(q.x & 0xffff0000u), w, o[1]);
    o[2] = fmaf(__uint_as_float(q.y << 16), w, o[2]);
    o[3] = fmaf(__uint_as_float(q.y & 0xffff0000u), w, o[3]);
    o[4] = fmaf(__uint_as_float(q.z << 16), w, o[4]);
    o[5] = fmaf(__uint_as_float(q.z & 0xffff0000u), w, o[5]);
    o[6] = fmaf(__uint_as_float(q.w << 16), w, o[6]);
    o[7] = fmaf(__uint_as_float(q.w & 0xffff0000u), w, o[7]);
}

// ---------------------------------------------------------------------------
// Base build: seg A converts grid0 fp32 -> S0L0 bf16;
//             seg B down2 grid1 fp32 -> S1L1 bf16;
//             seg C down4 grid2 fp32 -> S2L2 bf16 (skips never-sampled S2L1).
// One thread per output texel. All three out blocks are 3*512^2 texels.
// ---------------------------------------------------------------------------
__global__ void __launch_bounds__(BLK) base_build_kernel(
    const float* __restrict__ g0, const float* __restrict__ g1,
    const float* __restrict__ g2, uint4* __restrict__ wsT,
    int bA, int bB, int bC) {
    int j = blockIdx.x * BLK + threadIdx.x;
    if (j >= bC) return;
    if (j < bA) {
        const float4* sp = (const float4*)g0 + (size_t)j * 2;
        float4 a = sp[0], b = sp[1];
        float o[8] = {a.x, a.y, a.z, a.w, b.x, b.y, b.z, b.w};
        wsT[T0 + j] = pack8(o);
    } else if (j < bB) {
        int t = j - bA;                       // sz=512, src S=1024, fp32
        int p = t >> 18;
        int rem = t & ((1 << 18) - 1);
        int y = rem >> 9;
        int x = rem & 511;
        const float4* sp = (const float4*)g1 + (size_t)p * 1024 * 1024 * 2;
        float o[8] = {0, 0, 0, 0, 0, 0, 0, 0};
#pragma unroll
        for (int dy = 0; dy < 2; ++dy) {
#pragma unroll
            for (int dx = 0; dx < 2; ++dx) {
                size_t idx = ((size_t)(2 * y + dy) * 1024 + (2 * x + dx)) * 2;
                float4 a = sp[idx], b = sp[idx + 1];
                o[0] += a.x; o[1] += a.y; o[2] += a.z; o[3] += a.w;
                o[4] += b.x; o[5] += b.y; o[6] += b.z; o[7] += b.w;
            }
        }
#pragma unroll
        for (int c = 0; c < 8; ++c) o[c] *= 0.25f;
        wsT[T1 + t] = pack8(o);
    } else {
        int t = j - bB;                       // sz=512, src S=2048, fp32, 4x4
        int p = t >> 18;
        int rem = t & ((1 << 18) - 1);
        int y = rem >> 9;
        int x = rem & 511;
        const float4* sp = (const float4*)g2 + (size_t)p * 2048 * 2048 * 2;
        float o[8] = {0, 0, 0, 0, 0, 0, 0, 0};
#pragma unroll
        for (int dy = 0; dy < 4; ++dy) {
#pragma unroll
            for (int dx = 0; dx < 4; ++dx) {
                size_t idx = ((size_t)(4 * y + dy) * 2048 + (4 * x + dx)) * 2;
                float4 a = sp[idx], b = sp[idx + 1];
                o[0] += a.x; o[1] += a.y; o[2] += a.z; o[3] += a.w;
                o[4] += b.x; o[5] += b.y; o[6] += b.z; o[7] += b.w;
            }
        }
#pragma unroll
        for (int c = 0; c < 8; ++c) o[c] *= 0.0625f;
        wsT[T2 + t] = pack8(o);
    }
}

// 2x2 box downsample, bf16 -> bf16, up to 3 segments (texel offsets into wsT).
__global__ void __launch_bounds__(BLK) down2b_kernel(
    uint4* __restrict__ wsT,
    int srcA, int dstA, int lszA, int bA,
    int srcB, int dstB, int lszB, int bB,
    int srcC, int dstC, int lszC, int bC) {
    int j = blockIdx.x * BLK + threadIdx.x;
    if (j >= bC) return;
    int src, dst, lsz;
    if (j < bA) {
        src = srcA; dst = dstA; lsz = lszA;
    } else if (j < bB) {
        src = srcB; dst = dstB; lsz = lszB; j -= bA;
    } else {
        src = srcC; dst = dstC; lsz = lszC; j -= bB;
    }
    int sz = 1 << lsz;
    int p = j >> (2 * lsz);
    int rem = j & (sz * sz - 1);
    int y = rem >> lsz;
    int x = rem & (sz - 1);
    int S = sz << 1;
    const uint4* sp = wsT + src + (size_t)p * S * S;
    size_t i00 = (size_t)(2 * y) * S + 2 * x;
    float d0[8], d1[8], d2[8], d3[8];
    dec8(sp[i00], d0);
    dec8(sp[i00 + 1], d1);
    dec8(sp[i00 + S], d2);
    dec8(sp[i00 + S + 1], d3);
    float o[8];
#pragma unroll
    for (int c = 0; c < 8; ++c) o[c] = (d0[c] + d1[c] + d2[c] + d3[c]) * 0.25f;
    wsT[dst + (size_t)(p << (2 * lsz)) + rem] = pack8(o);
}

// ---------------------------------------------------------------------------
// Sampling: one thread per (sample, scale). 3 planes x 2 mip levels x 4 taps,
// each tap one uint4 (16B bf16 texel). Blend in fp32, write 24 floats.
// ---------------------------------------------------------------------------
__device__ __forceinline__ void bilerp16(const uint4* __restrict__ t, int sz,
                                         float u, float v, float o[8]) {
    float fsz = (float)sz;
    float px = u * fsz - 0.5f;
    float py = v * fsz - 0.5f;
    float x0f = floorf(px), y0f = floorf(py);
    float fx = px - x0f, fy = py - y0f;
    int xi = (int)x0f, yi = (int)y0f;
    int m = sz - 1;
    int x0 = min(max(xi, 0), m);
    int x1 = min(max(xi + 1, 0), m);
    int y0 = min(max(yi, 0), m);
    int y1 = min(max(yi + 1, 0), m);
    const uint4* r0 = t + (size_t)y0 * sz;
    const uint4* r1 = t + (size_t)y1 * sz;
    uint4 q00 = r0[x0];
    uint4 q01 = r0[x1];
    uint4 q10 = r1[x0];
    uint4 q11 = r1[x1];
    float w00 = (1.0f - fx) * (1.0f - fy);
    float w01 = fx * (1.0f - fy);
    float w10 = (1.0f - fx) * fy;
    float w11 = fx * fy;
#pragma unroll
    for (int c = 0; c < 8; ++c) o[c] = 0.0f;
    acc8(q00, w00, o);
    acc8(q01, w01, o);
    acc8(q10, w10, o);
    acc8(q11, w11, o);
}

__global__ void __launch_bounds__(BLK) tex_sample_kernel(
    const float* __restrict__ xin, const float* __restrict__ level,
    const uint4* __restrict__ wsT, float* __restrict__ out, int n3) {
    int tid = blockIdx.x * BLK + threadIdx.x;
    if (tid >= n3) return;
    int i = tid / 3;
    int s = tid - 3 * i;
    float xv0 = xin[3 * i + 0];
    float xv1 = xin[3 * i + 1];
    float xv2 = xin[3 * i + 2];
    float lev = level[i];

    const int WSS_[3] = {T0, T1, T2};
    const int OFFMIN_[3] = {0, 1048576, 5242880};

    const int R = 512 << s;
    float bias = lev + 9.0f + (float)s;
    float lvl = fminf(fmaxf(bias, 0.0f), 7.0f);
    float l0f = floorf(lvl);
    int l0 = (int)l0f;
    int l1 = min(l0 + 1, 7);
    float f = lvl - l0f;
    int sz0 = R >> l0;
    int sz1 = R >> l1;
    int off0 = ((R * R - sz0 * sz0) * 4) / 3;
    int off1 = ((R * R - sz1 * sz1) * 4) / 3;
    const uint4* base0 = wsT + WSS_[s] + (size_t)3 * (off0 - OFFMIN_[s]);
    const uint4* base1 = wsT + WSS_[s] + (size_t)3 * (off1 - OFFMIN_[s]);

    float* op = out + (size_t)i * 72 + s * 24;
    float omf = 1.0f - f;

#pragma unroll
    for (int p = 0; p < 3; ++p) {
        float u = (p == 0) ? xv1 : xv0;
        float v = (p == 2) ? xv1 : xv2;
        const uint4* t0 = base0 + (size_t)p * (sz0 * sz0);
        const uint4* t1 = base1 + (size_t)p * (sz1 * sz1);
        float a[8], b[8];
        bilerp16(t0, sz0, u, v, a);
        bilerp16(t1, sz1, u, v, b);
        float4 r0, r1;
        r0.x = a[0] * omf + b[0] * f;
        r0.y = a[1] * omf + b[1] * f;
        r0.z = a[2] * omf + b[2] * f;
        r0.w = a[3] * omf + b[3] * f;
        r1.x = a[4] * omf + b[4] * f;
        r1.y = a[5] * omf + b[5] * f;
        r1.z = a[6] * omf + b[6] * f;
        r1.w = a[7] * omf + b[7] * f;
        float4* o4 = (float4*)(op + p * 8);
        o4[0] = r0;
        o4[1] = r1;
    }
}

extern "C" void kernel_launch(void* const* d_in, const int* in_sizes, int n_in,
                              void* d_out, int out_size, void* d_ws, size_t ws_size,
                              hipStream_t stream) {
    const float* x = (const float*)d_in[0];
    const float* level = (const float*)d_in[1];
    const float* g0 = (const float*)d_in[2];
    const float* g1 = (const float*)d_in[3];
    const float* g2 = (const float*)d_in[4];
    float* out = (float*)d_out;
    uint4* wsT = (uint4*)d_ws;
    int n = in_sizes[0] / 3;

    // ws texel offset of level block (s, l)
    auto lvlOff = [](int s, int l) -> int {
        const int WSS[3] = {T0, T1, T2};
        const int OFFMIN[3] = {0, 1048576, 5242880};
        int R = 512 << s;
        int sz = R >> l;
        int off = ((R * R - sz * sz) * 4) / 3;
        return WSS[s] + 3 * (off - OFFMIN[s]);
    };

    // base levels: S0L0 (convert), S1L1 (down2 fp32), S2L2 (down4 fp32)
    {
        int bA = 3 * 512 * 512;
        int bB = bA * 2;
        int bC = bA * 3;
        base_build_kernel<<<(bC + BLK - 1) / BLK, BLK, 0, stream>>>(
            g0, g1, g2, wsT, bA, bB, bC);
    }
    // chain: l = 1..7
    for (int l = 1; l <= 7; ++l) {
        // segment A: scale0 (levels 1..7), B: scale1 (2..7), C: scale2 (3..7)
        int szA = 512 >> l;
        int bA = 3 * szA * szA;
        int srcA = lvlOff(0, l - 1), dstA = lvlOff(0, l), lszA = 9 - l;
        int bB = bA, srcB = 0, dstB = 0, lszB = 0;
        int bC = bA, srcC = 0, dstC = 0, lszC = 0;
        if (l >= 2) {
            int szB = 1024 >> l;
            bB = bA + 3 * szB * szB;
            srcB = lvlOff(1, l - 1); dstB = lvlOff(1, l); lszB = 10 - l;
            bC = bB;
        }
        if (l >= 3) {
            int szC = 2048 >> l;
            bC = bB + 3 * szC * szC;
            srcC = lvlOff(2, l - 1); dstC = lvlOff(2, l); lszC = 11 - l;
        }
        down2b_kernel<<<(bC + BLK - 1) / BLK, BLK, 0, stream>>>(
            wsT, srcA, dstA, lszA, bA, srcB, dstB, lszB, bB, srcC, dstC, lszC, bC);
    }

    // sampling: one thread per (sample, scale)
    int n3 = 3 * n;
    tex_sample_kernel<<<(n3 + BLK - 1) / BLK, BLK, 0, stream>>>(
        x, level, wsT, out, n3);
}